// Round 5
// baseline (699.394 us; speedup 1.0000x reference)
//
#include <hip/hip_runtime.h>
#include <stdint.h>

#define L_DIM 2048
#define B_DIM 16
#define D_DIM 1024
#define M_DIM 32768              // L*B
#define K_DIM 1024               // D
#define N_DIM 3072               // 3D
#define SCALE_X 1.7320508075688772f

typedef __attribute__((ext_vector_type(8))) short short8;
typedef __attribute__((ext_vector_type(8))) unsigned short ushort8;
typedef __attribute__((ext_vector_type(4))) float f32x4;

__device__ __forceinline__ float bf2f(uint32_t b) {
    union { uint32_t u; float f; } v; v.u = b << 16; return v.f;
}
__device__ __forceinline__ uint16_t f2bf(float f) {
    union { float f; uint32_t u; } v; v.f = f;
    uint32_t u = v.u;
    return (uint16_t)((u + 0x7FFFu + ((u >> 16) & 1u)) >> 16);  // RNE
}

// async global->LDS, 16B per lane. LDS dest is wave-uniform base + lane*16.
__device__ __forceinline__ void gl16(const uint16_t* g, uint16_t* l) {
    __builtin_amdgcn_global_load_lds(
        (const __attribute__((address_space(1))) void*)g,
        (__attribute__((address_space(3))) void*)l,
        16 /*literal*/, 0, 0);
}

// full fence: IR-level memory barrier + MIR scheduling barrier.
__device__ __forceinline__ void fence_all() {
    asm volatile("" ::: "memory");
    __builtin_amdgcn_sched_barrier(0);
}
__device__ __forceinline__ void barrier_hard() {
    fence_all();
    __builtin_amdgcn_s_barrier();
    fence_all();
}

// ---- prep: weight (K x N fp32) -> Wt (N x K bf16) via 32x32 LDS tile ----
__global__ void __launch_bounds__(256)
prep_w_kernel(const float* __restrict__ w, uint16_t* __restrict__ wt) {
    __shared__ uint16_t tile[32][33];            // +1 pad breaks bank conflicts
    int bid = blockIdx.x;
    int kt = (bid & 31) * 32;                    // K/32 = 32
    int nt = (bid >> 5) * 32;                    // N/32 = 96
    int tx = threadIdx.x & 31;
    int ty = threadIdx.x >> 5;                   // 0..7
#pragma unroll
    for (int r = 0; r < 32; r += 8)
        tile[ty + r][tx] = f2bf(w[(size_t)(kt + ty + r) * N_DIM + nt + tx]);
    __syncthreads();
#pragma unroll
    for (int r = 0; r < 32; r += 8)
        wt[(size_t)(nt + ty + r) * K_DIM + kt + tx] = tile[tx][ty + r];
}

// ---- prep: x (M x K fp32) -> xb (M x K bf16) ----
__global__ void __launch_bounds__(256)
prep_x_kernel(const float* __restrict__ x, uint16_t* __restrict__ xb) {
    size_t i = (size_t)blockIdx.x * 256 + threadIdx.x;
    const float4 a = *(const float4*)(x + i * 8);
    const float4 b = *(const float4*)(x + i * 8 + 4);
    ushort8 o;
    o[0] = f2bf(a.x); o[1] = f2bf(a.y); o[2] = f2bf(a.z); o[3] = f2bf(a.w);
    o[4] = f2bf(b.x); o[5] = f2bf(b.y); o[6] = f2bf(b.z); o[7] = f2bf(b.w);
    *(ushort8*)(xb + i * 8) = o;
}

// ================= 256x256 8-phase GEMM (T2+T3+T4+T5), hardened =================
// (unchanged from R3 — verified passing)
__global__ void __launch_bounds__(512, 2)
gemm_8ph_kernel(const uint16_t* __restrict__ Ab,  // x bf16, M x K
                const uint16_t* __restrict__ Bt,  // Wt bf16, N x K
                uint16_t* __restrict__ u01,       // M x D x 2 (aliases d_out)
                uint16_t* __restrict__ u2p)       // M x D (ws)
{
    __shared__ uint16_t lds[65536];               // 128 KiB

    int bid = blockIdx.x;
    int mg = bid / 96;
    int tt = bid - mg * 96;
    int ntile = tt >> 3;
    int mtile = mg * 8 + (tt & 7);
    int m0 = mtile * 256;
    int n0 = ntile * 256;

    int t = threadIdx.x;
    int lane = t & 63;
    int w = t >> 6;
    int wm = (w >> 2) * 128;
    int wn = (w & 3) * 64;

    int row0 = t >> 3;
    int slot = t & 7;
    int swz_c = (slot ^ (row0 & 7)) * 8;
    const uint16_t* pA = Ab + (((size_t)(m0 + row0)) << 10) + swz_c;
    const uint16_t* pB = Bt + (((size_t)(n0 + row0)) << 10) + swz_c;

    int frow = lane & 15;
    int fkb = (lane >> 4) * 16;

    f32x4 acc[8][4] = {};
    short8 aF[4][2];
    short8 bF[4][2];

#define STAGE(hh, Tn) { \
    const uint16_t* gs = (((hh) < 2) ? pA : pB) + ((size_t)((hh) & 1) * 131072) + (size_t)(Tn) * 64; \
    uint16_t* ld = lds + nxtO + (hh) * 8192 + t * 8; \
    gl16(gs, ld); gl16(gs + 65536, ld + 4096); }

#define RD_A(mh) { \
    _Pragma("unroll") for (int mf = 0; mf < 4; mf++) \
    _Pragma("unroll") for (int ks = 0; ks < 2; ks++) { \
        int r = wm + (mh) * 64 + mf * 16 + frow; \
        int cb = (ks * 64 + fkb) ^ ((r & 7) << 4); \
        aF[mf][ks] = *(const short8*)(lds + curA + r * 64 + (cb >> 1)); } }

#define RD_B() { \
    _Pragma("unroll") for (int nf = 0; nf < 4; nf++) \
    _Pragma("unroll") for (int ks = 0; ks < 2; ks++) { \
        int r = wn + nf * 16 + frow; \
        int cb = (ks * 64 + fkb) ^ ((r & 7) << 4); \
        bF[nf][ks] = *(const short8*)(lds + curB + r * 64 + (cb >> 1)); } }

#define QM(mh, nh) { \
    __builtin_amdgcn_s_setprio(1); \
    _Pragma("unroll") for (int mf = 0; mf < 4; mf++) \
    _Pragma("unroll") for (int nj = 0; nj < 2; nj++) \
    _Pragma("unroll") for (int ks = 0; ks < 2; ks++) \
        acc[(mh) * 4 + mf][(nh) * 2 + nj] = __builtin_amdgcn_mfma_f32_16x16x32_bf16( \
            aF[mf][ks], bF[(nh) * 2 + nj][ks], acc[(mh) * 4 + mf][(nh) * 2 + nj], 0, 0, 0); \
    __builtin_amdgcn_s_setprio(0); }

    {
        int nxtO = 0;
        STAGE(0, 0); STAGE(1, 0); STAGE(2, 0); STAGE(3, 0);
    }

    for (int T = 0; T < 15; ++T) {
        int cur = T & 1;
        int curA = cur * 32768;
        int curB = curA + 16384;
        int nxtO = (cur ^ 1) * 32768;

        barrier_hard();                               // all reads of buf[nxt] done
        STAGE(0, T + 1);
        fence_all();
        asm volatile("s_waitcnt vmcnt(2)" ::: "memory");
        barrier_hard();                               // publish tile T
        RD_B();
        RD_A(0);
        QM(0, 0);
        fence_all();
        STAGE(1, T + 1);
        fence_all();
        QM(0, 1);
        RD_A(1);
        fence_all();
        STAGE(2, T + 1);
        fence_all();
        QM(1, 1);
        fence_all();
        STAGE(3, T + 1);
        fence_all();
        QM(1, 0);
    }

    {
        int curA = 32768;
        int curB = curA + 16384;
        barrier_hard();
        asm volatile("s_waitcnt vmcnt(0)" ::: "memory");
        barrier_hard();
        RD_B();
        RD_A(0);
        QM(0, 0);
        QM(0, 1);
        RD_A(1);
        QM(1, 1);
        QM(1, 0);
    }

#undef STAGE
#undef RD_A
#undef RD_B
#undef QM

    int colf = lane & 15;
    int rowq = (lane >> 4) * 4;
#pragma unroll
    for (int i = 0; i < 8; i++) {
#pragma unroll
        for (int j = 0; j < 4; j++) {
            int gcol = n0 + wn + j * 16 + colf;
            int dq = gcol / 3;
            int cm = gcol - dq * 3;
#pragma unroll
            for (int r = 0; r < 4; r++) {
                int grow = m0 + wm + i * 16 + rowq + r;
                uint16_t v = f2bf(acc[i][j][r]);
                if (cm < 2) u01[(size_t)grow * 2048 + dq * 2 + cm] = v;
                else        u2p[(size_t)grow * 1024 + dq] = v;
            }
        }
    }
}

// ---- fallback GEMM (ws too small for xb): 128^2, A fp32 in-register cvt ----
__global__ void __launch_bounds__(256)
gemm_kernel(const float* __restrict__ A32,
            const uint16_t* __restrict__ Bt,
            uint16_t* __restrict__ u01,
            uint16_t* __restrict__ u2p)
{
    __shared__ uint16_t As[128 * 32];
    __shared__ uint16_t Bs[128 * 32];

    int bid = blockIdx.x;
    int mg = bid / 192;
    int tt = bid - mg * 192;
    int ntile = tt >> 3;
    int mtile = mg * 8 + (tt & 7);
    int m0 = mtile * 128;
    int n0 = ntile * 128;

    int t = threadIdx.x;
    int lane = t & 63;
    int w = t >> 6;
    int wm = (w >> 1) * 64;
    int wn = (w & 1) * 64;

    f32x4 acc[4][4] = {};

    int frow = lane & 15;
    int fk = (lane >> 4) * 8;

    for (int kt = 0; kt < K_DIM; kt += 32) {
#pragma unroll
        for (int c = 0; c < 4; c++) {
            int idx = c * 256 + t;
            int row = idx >> 3;
            int ko = (idx & 7) * 4;
            float4 v = *(const float4*)(A32 + (size_t)(m0 + row) * K_DIM + kt + ko);
            ushort4 o;
            o.x = f2bf(v.x); o.y = f2bf(v.y); o.z = f2bf(v.z); o.w = f2bf(v.w);
            *(ushort4*)(As + row * 32 + ko) = o;
        }
#pragma unroll
        for (int c = 0; c < 2; c++) {
            int idx = c * 256 + t;
            int row = idx >> 2;
            int ko = (idx & 3) * 8;
            short8 v = *(const short8*)(Bt + (size_t)(n0 + row) * K_DIM + kt + ko);
            *(short8*)(Bs + row * 32 + ko) = v;
        }
        __syncthreads();

        short8 af[4], bfr[4];
#pragma unroll
        for (int i = 0; i < 4; i++) {
            af[i]  = *(const short8*)(As + (wm + i * 16 + frow) * 32 + fk);
            bfr[i] = *(const short8*)(Bs + (wn + i * 16 + frow) * 32 + fk);
        }
#pragma unroll
        for (int i = 0; i < 4; i++)
#pragma unroll
            for (int j = 0; j < 4; j++)
                acc[i][j] = __builtin_amdgcn_mfma_f32_16x16x32_bf16(af[i], bfr[j], acc[i][j], 0, 0, 0);
        __syncthreads();
    }

    int colf = lane & 15;
    int rowq = (lane >> 4) * 4;
#pragma unroll
    for (int i = 0; i < 4; i++) {
#pragma unroll
        for (int j = 0; j < 4; j++) {
            int gcol = n0 + wn + j * 16 + colf;
            int dq = gcol / 3;
            int cm = gcol - dq * 3;
#pragma unroll
            for (int r = 0; r < 4; r++) {
                int grow = m0 + wm + i * 16 + rowq + r;
                uint16_t v = f2bf(acc[i][j][r]);
                if (cm < 2) u01[(size_t)grow * 2048 + dq * 2 + cm] = v;
                else        u2p[(size_t)grow * 1024 + dq] = v;
            }
        }
    }
}

// ---- scan_c: serial c-recurrence + r-gate ARG materialization. ----
// Reference semantics: r = sigmoid(u2 + rb + c_PREV*rw)  (previous state!).
// Per step: load u01 (4B) + u2 (2B); f-gate update (critical chain);
// rarg = u2 + rb + c_prev*rw (off-chain); store c_new fp32 in-place over the
// consumed u01 dword (write row l, reads rows >= l+P) and bf16(rarg) in-place
// over the consumed u2 (same discipline; same-type uint16 accesses).
__global__ void __launch_bounds__(64)
scan_c_kernel(const uint32_t* u01,              // M x D of {u0,u1} (aliases out)
              uint16_t* u2io,                   // in: u2 bf16; out: rarg bf16
              const float* __restrict__ c0,
              const float* __restrict__ wc,
              const float* __restrict__ bias,
              float* out)                       // c per (l,cid) in-place, then c_final
{
    int cid = blockIdx.x * 64 + threadIdx.x;       // b*1024 + d
    int d = cid & (D_DIM - 1);
    float fw = wc[d], rw = wc[D_DIM + d];
    float fb = bias[d], rb = bias[D_DIM + d];
    float c = c0[cid];

    constexpr int P = 16;
    const int STEP = B_DIM * D_DIM;                // 16384
    uint32_t b01[P];
    uint16_t b2[P];
#pragma unroll
    for (int j = 0; j < P; j++) {
        b01[j] = u01[cid + j * STEP];
        b2[j]  = u2io[cid + j * STEP];
    }

    for (int lb = 0; lb < L_DIM; lb += P) {
#pragma unroll
        for (int j = 0; j < P; j++) {
            int l = lb + j;
            uint32_t v01 = b01[j];
            float u2 = bf2f((uint32_t)b2[j]);

            int ln = l + P; if (ln > L_DIM - 1) ln = L_DIM - 1;
            b01[j] = u01[cid + ln * STEP];
            b2[j]  = u2io[cid + ln * STEP];

            float u0 = bf2f(v01 & 0xFFFFu);
            float u1 = bf2f(v01 >> 16);
            float cp = c;                              // c_prev
            float ef = __expf(-(u1 + fb + cp * fw));
            float f = __builtin_amdgcn_rcpf(1.0f + ef);
            c = u0 + (cp - u0) * f;                    // c_new
            float rarg = u2 + rb + cp * rw;            // r-gate arg from c_PREV
            out[l * STEP + cid] = c;
            u2io[l * STEP + cid] = f2bf(rarg);
        }
    }
    out[L_DIM * STEP + cid] = c;
}

// ---- h: fully parallel, BW-bound. h = xp + (c_new - xp) * sigmoid(rarg). ----
__global__ void __launch_bounds__(256)
h_kernel(float* out,                            // in: c_new fp32; out: h (in-place)
         const uint16_t* __restrict__ rargp,    // M x D bf16 rarg
         const float* __restrict__ x)           // fp32 x
{
    size_t i = ((size_t)blockIdx.x * 256 + threadIdx.x) * 4;   // over M*D

    f32x4 cv = *(const f32x4*)(out + i);
    f32x4 xv = *(const f32x4*)(x + i);
    ushort4 uv = *(const ushort4*)(rargp + i);

    float ra[4] = { bf2f(uv.x), bf2f(uv.y), bf2f(uv.z), bf2f(uv.w) };
    f32x4 h;
#pragma unroll
    for (int e = 0; e < 4; e++) {
        float xp = xv[e] * SCALE_X;
        float er = __expf(-ra[e]);
        float r = __builtin_amdgcn_rcpf(1.0f + er);
        h[e] = xp + (cv[e] - xp) * r;
    }
    *(f32x4*)(out + i) = h;
}

extern "C" void kernel_launch(void* const* d_in, const int* in_sizes, int n_in,
                              void* d_out, int out_size, void* d_ws, size_t ws_size,
                              hipStream_t stream) {
    const float* x    = (const float*)d_in[0];
    const float* c0   = (const float*)d_in[1];
    const float* w    = (const float*)d_in[2];
    const float* wc   = (const float*)d_in[3];
    const float* bias = (const float*)d_in[4];

    // ws layout: wt 6 MB | u2 64 MB | xb 64 MB (fast path only)
    uint16_t* wt  = (uint16_t*)d_ws;
    uint16_t* u2p = (uint16_t*)((char*)d_ws + 6291456);
    const size_t XB_OFF = 6291456 + (size_t)M_DIM * D_DIM * 2;   // 70 MB
    const size_t WS_NEED = XB_OFF + (size_t)M_DIM * K_DIM * 2;   // 134 MB

    uint16_t* u01 = (uint16_t*)d_out;
    float* out = (float*)d_out;

    prep_w_kernel<<<(K_DIM / 32) * (N_DIM / 32), 256, 0, stream>>>(w, wt);

    if (ws_size >= WS_NEED) {
        uint16_t* xb = (uint16_t*)((char*)d_ws + XB_OFF);
        prep_x_kernel<<<(M_DIM * K_DIM / 8) / 256, 256, 0, stream>>>(x, xb);
        gemm_8ph_kernel<<<(M_DIM / 256) * (N_DIM / 256), 512, 0, stream>>>(xb, wt, u01, u2p);
    } else {
        gemm_kernel<<<(M_DIM / 128) * (N_DIM / 128), 256, 0, stream>>>(x, wt, u01, u2p);
    }

    scan_c_kernel<<<(B_DIM * D_DIM) / 64, 64, 0, stream>>>((const uint32_t*)u01, u2p,
                                                           c0, wc, bias, out);
    h_kernel<<<(M_DIM * D_DIM / 4) / 256, 256, 0, stream>>>(out, u2p, x);
}

// Round 6
// 641.973 us; speedup vs baseline: 1.0894x; 1.0894x over previous
//
#include <hip/hip_runtime.h>
#include <stdint.h>

#define L_DIM 2048
#define B_DIM 16
#define D_DIM 1024
#define M_DIM 32768              // L*B
#define K_DIM 1024               // D
#define N_DIM 3072               // 3D
#define SCALE_X 1.7320508075688772f

typedef __attribute__((ext_vector_type(8))) short short8;
typedef __attribute__((ext_vector_type(8))) unsigned short ushort8;
typedef __attribute__((ext_vector_type(4))) float f32x4;
typedef __attribute__((ext_vector_type(4))) unsigned int u32x4;

__device__ __forceinline__ float bf2f(uint32_t b) {
    union { uint32_t u; float f; } v; v.u = b << 16; return v.f;
}
__device__ __forceinline__ uint16_t f2bf(float f) {
    union { float f; uint32_t u; } v; v.f = f;
    uint32_t u = v.u;
    return (uint16_t)((u + 0x7FFFu + ((u >> 16) & 1u)) >> 16);  // RNE
}

// async global->LDS, 16B per lane. LDS dest is wave-uniform base + lane*16.
__device__ __forceinline__ void gl16(const uint16_t* g, uint16_t* l) {
    __builtin_amdgcn_global_load_lds(
        (const __attribute__((address_space(1))) void*)g,
        (__attribute__((address_space(3))) void*)l,
        16 /*literal*/, 0, 0);
}

// full fence: IR-level memory barrier + MIR scheduling barrier.
__device__ __forceinline__ void fence_all() {
    asm volatile("" ::: "memory");
    __builtin_amdgcn_sched_barrier(0);
}
__device__ __forceinline__ void barrier_hard() {
    fence_all();
    __builtin_amdgcn_s_barrier();
    fence_all();
}

// weight-column permutation: original n = 3d+comp -> storage col s so the
// gemm epilogue writes contiguously: s = comp<2 ? 2d+comp : 2048+d.
// u01 plane = cols [0,2048) (pairs per d), u2 plane = cols [2048,3072).
__device__ __forceinline__ int perm_n(int n) {
    int dq = n / 3;
    int cm = n - dq * 3;
    return (cm < 2) ? (dq * 2 + cm) : (2048 + dq);
}

// ---- prep: weight (K x N fp32) -> Wt (S x K bf16) with permuted rows ----
__global__ void __launch_bounds__(256)
prep_w_kernel(const float* __restrict__ w, uint16_t* __restrict__ wt) {
    __shared__ uint16_t tile[32][33];            // +1 pad breaks bank conflicts
    int bid = blockIdx.x;
    int kt = (bid & 31) * 32;                    // K/32 = 32
    int nt = (bid >> 5) * 32;                    // N/32 = 96
    int tx = threadIdx.x & 31;
    int ty = threadIdx.x >> 5;                   // 0..7
#pragma unroll
    for (int r = 0; r < 32; r += 8)
        tile[ty + r][tx] = f2bf(w[(size_t)(kt + ty + r) * N_DIM + nt + tx]);
    __syncthreads();
#pragma unroll
    for (int r = 0; r < 32; r += 8) {
        int s = perm_n(nt + ty + r);
        wt[(size_t)s * K_DIM + kt + tx] = tile[tx][ty + r];
    }
}

// ---- prep: x (M x K fp32) -> xb (M x K bf16) ----
__global__ void __launch_bounds__(256)
prep_x_kernel(const float* __restrict__ x, uint16_t* __restrict__ xb) {
    size_t i = (size_t)blockIdx.x * 256 + threadIdx.x;
    const float4 a = *(const float4*)(x + i * 8);
    const float4 b = *(const float4*)(x + i * 8 + 4);
    ushort8 o;
    o[0] = f2bf(a.x); o[1] = f2bf(a.y); o[2] = f2bf(a.z); o[3] = f2bf(a.w);
    o[4] = f2bf(b.x); o[5] = f2bf(b.y); o[6] = f2bf(b.z); o[7] = f2bf(b.w);
    *(ushort8*)(xb + i * 8) = o;
}

// ================= 256x256 8-phase GEMM (T2+T3+T4+T5), hardened =================
// (schedule unchanged from R5 — verified passing; epilogue now contiguous via
// the weight permutation: storage col == gcol, region branch wave-uniform)
__global__ void __launch_bounds__(512, 2)
gemm_8ph_kernel(const uint16_t* __restrict__ Ab,  // x bf16, M x K
                const uint16_t* __restrict__ Bt,  // Wt bf16, S x K (permuted)
                uint16_t* __restrict__ u01,       // M x 2048 (aliases d_out)
                uint16_t* __restrict__ u2p)       // M x 1024 (ws)
{
    __shared__ uint16_t lds[65536];               // 128 KiB

    int bid = blockIdx.x;
    int mg = bid / 96;
    int tt = bid - mg * 96;
    int ntile = tt >> 3;
    int mtile = mg * 8 + (tt & 7);
    int m0 = mtile * 256;
    int n0 = ntile * 256;

    int t = threadIdx.x;
    int lane = t & 63;
    int w = t >> 6;
    int wm = (w >> 2) * 128;
    int wn = (w & 3) * 64;

    int row0 = t >> 3;
    int slot = t & 7;
    int swz_c = (slot ^ (row0 & 7)) * 8;
    const uint16_t* pA = Ab + (((size_t)(m0 + row0)) << 10) + swz_c;
    const uint16_t* pB = Bt + (((size_t)(n0 + row0)) << 10) + swz_c;

    int frow = lane & 15;
    int fkb = (lane >> 4) * 16;

    f32x4 acc[8][4] = {};
    short8 aF[4][2];
    short8 bF[4][2];

#define STAGE(hh, Tn) { \
    const uint16_t* gs = (((hh) < 2) ? pA : pB) + ((size_t)((hh) & 1) * 131072) + (size_t)(Tn) * 64; \
    uint16_t* ld = lds + nxtO + (hh) * 8192 + t * 8; \
    gl16(gs, ld); gl16(gs + 65536, ld + 4096); }

#define RD_A(mh) { \
    _Pragma("unroll") for (int mf = 0; mf < 4; mf++) \
    _Pragma("unroll") for (int ks = 0; ks < 2; ks++) { \
        int r = wm + (mh) * 64 + mf * 16 + frow; \
        int cb = (ks * 64 + fkb) ^ ((r & 7) << 4); \
        aF[mf][ks] = *(const short8*)(lds + curA + r * 64 + (cb >> 1)); } }

#define RD_B() { \
    _Pragma("unroll") for (int nf = 0; nf < 4; nf++) \
    _Pragma("unroll") for (int ks = 0; ks < 2; ks++) { \
        int r = wn + nf * 16 + frow; \
        int cb = (ks * 64 + fkb) ^ ((r & 7) << 4); \
        bF[nf][ks] = *(const short8*)(lds + curB + r * 64 + (cb >> 1)); } }

#define QM(mh, nh) { \
    __builtin_amdgcn_s_setprio(1); \
    _Pragma("unroll") for (int mf = 0; mf < 4; mf++) \
    _Pragma("unroll") for (int nj = 0; nj < 2; nj++) \
    _Pragma("unroll") for (int ks = 0; ks < 2; ks++) \
        acc[(mh) * 4 + mf][(nh) * 2 + nj] = __builtin_amdgcn_mfma_f32_16x16x32_bf16( \
            aF[mf][ks], bF[(nh) * 2 + nj][ks], acc[(mh) * 4 + mf][(nh) * 2 + nj], 0, 0, 0); \
    __builtin_amdgcn_s_setprio(0); }

    {
        int nxtO = 0;
        STAGE(0, 0); STAGE(1, 0); STAGE(2, 0); STAGE(3, 0);
    }

    for (int T = 0; T < 15; ++T) {
        int cur = T & 1;
        int curA = cur * 32768;
        int curB = curA + 16384;
        int nxtO = (cur ^ 1) * 32768;

        barrier_hard();                               // all reads of buf[nxt] done
        STAGE(0, T + 1);
        fence_all();
        asm volatile("s_waitcnt vmcnt(2)" ::: "memory");
        barrier_hard();                               // publish tile T
        RD_B();
        RD_A(0);
        QM(0, 0);
        fence_all();
        STAGE(1, T + 1);
        fence_all();
        QM(0, 1);
        RD_A(1);
        fence_all();
        STAGE(2, T + 1);
        fence_all();
        QM(1, 1);
        fence_all();
        STAGE(3, T + 1);
        fence_all();
        QM(1, 0);
    }

    {
        int curA = 32768;
        int curB = curA + 16384;
        barrier_hard();
        asm volatile("s_waitcnt vmcnt(0)" ::: "memory");
        barrier_hard();
        RD_B();
        RD_A(0);
        QM(0, 0);
        QM(0, 1);
        RD_A(1);
        QM(1, 1);
        QM(1, 0);
    }

#undef STAGE
#undef RD_A
#undef RD_B
#undef QM

    // epilogue: storage col == gcol (permuted weights); contiguous 2B runs
    // per 16-lane group, region branch wave-uniform (2048 % 16 == 0).
    int colf = lane & 15;
    int rowq = (lane >> 4) * 4;
#pragma unroll
    for (int i = 0; i < 8; i++) {
#pragma unroll
        for (int j = 0; j < 4; j++) {
            int gcol = n0 + wn + j * 16 + colf;
#pragma unroll
            for (int r = 0; r < 4; r++) {
                int grow = m0 + wm + i * 16 + rowq + r;
                uint16_t v = f2bf(acc[i][j][r]);
                if (gcol < 2048) u01[(size_t)grow * 2048 + gcol] = v;
                else             u2p[(size_t)grow * 1024 + (gcol - 2048)] = v;
            }
        }
    }
}

// ---- fallback GEMM (ws too small for xb): 128^2, A fp32 in-register cvt ----
__global__ void __launch_bounds__(256)
gemm_kernel(const float* __restrict__ A32,
            const uint16_t* __restrict__ Bt,
            uint16_t* __restrict__ u01,
            uint16_t* __restrict__ u2p)
{
    __shared__ uint16_t As[128 * 32];
    __shared__ uint16_t Bs[128 * 32];

    int bid = blockIdx.x;
    int mg = bid / 192;
    int tt = bid - mg * 192;
    int ntile = tt >> 3;
    int mtile = mg * 8 + (tt & 7);
    int m0 = mtile * 128;
    int n0 = ntile * 128;

    int t = threadIdx.x;
    int lane = t & 63;
    int w = t >> 6;
    int wm = (w >> 1) * 64;
    int wn = (w & 1) * 64;

    f32x4 acc[4][4] = {};

    int frow = lane & 15;
    int fk = (lane >> 4) * 8;

    for (int kt = 0; kt < K_DIM; kt += 32) {
#pragma unroll
        for (int c = 0; c < 4; c++) {
            int idx = c * 256 + t;
            int row = idx >> 3;
            int ko = (idx & 7) * 4;
            float4 v = *(const float4*)(A32 + (size_t)(m0 + row) * K_DIM + kt + ko);
            ushort4 o;
            o.x = f2bf(v.x); o.y = f2bf(v.y); o.z = f2bf(v.z); o.w = f2bf(v.w);
            *(ushort4*)(As + row * 32 + ko) = o;
        }
#pragma unroll
        for (int c = 0; c < 2; c++) {
            int idx = c * 256 + t;
            int row = idx >> 2;
            int ko = (idx & 3) * 8;
            short8 v = *(const short8*)(Bt + (size_t)(n0 + row) * K_DIM + kt + ko);
            *(short8*)(Bs + row * 32 + ko) = v;
        }
        __syncthreads();

        short8 af[4], bfr[4];
#pragma unroll
        for (int i = 0; i < 4; i++) {
            af[i]  = *(const short8*)(As + (wm + i * 16 + frow) * 32 + fk);
            bfr[i] = *(const short8*)(Bs + (wn + i * 16 + frow) * 32 + fk);
        }
#pragma unroll
        for (int i = 0; i < 4; i++)
#pragma unroll
            for (int j = 0; j < 4; j++)
                acc[i][j] = __builtin_amdgcn_mfma_f32_16x16x32_bf16(af[i], bfr[j], acc[i][j], 0, 0, 0);
        __syncthreads();
    }

    int colf = lane & 15;
    int rowq = (lane >> 4) * 4;
#pragma unroll
    for (int i = 0; i < 4; i++) {
#pragma unroll
        for (int j = 0; j < 4; j++) {
            int gcol = n0 + wn + j * 16 + colf;
#pragma unroll
            for (int r = 0; r < 4; r++) {
                int grow = m0 + wm + i * 16 + rowq + r;
                uint16_t v = f2bf(acc[i][j][r]);
                if (gcol < 2048) u01[(size_t)grow * 2048 + gcol] = v;
                else             u2p[(size_t)grow * 1024 + (gcol - 2048)] = v;
            }
        }
    }
}

// ---- scan_c: serial c-recurrence, 1 load + 1 store per step. ----
// Per step: load packed {u0,u1} (4B); f-gate update (critical chain);
// store {bf16(c_prev), bf16(c_new)} packed as one dword IN-PLACE over the
// consumed u01 slot (write row l, reads rows >= l+P; final-block prefetches
// are dead). 2 vmem ops/step * P=16 = 32 outstanding (< 63 vmcnt limit --
// the old 4-op/step versions hit 64 and drained every step).
__global__ void __launch_bounds__(64)
scan_c_kernel(const uint32_t* u01,              // M x D of {u0,u1} (aliases out)
              uint32_t* cpack,                  // same buffer: {bf16 cp, bf16 c}
              const float* __restrict__ c0,
              const float* __restrict__ wc,
              const float* __restrict__ bias,
              float* out)                       // c_final fp32 tail
{
    int cid = blockIdx.x * 64 + threadIdx.x;       // b*1024 + d
    int d = cid & (D_DIM - 1);
    float fw = wc[d];
    float fb = bias[d];
    float c = c0[cid];

    constexpr int P = 16;
    const int STEP = B_DIM * D_DIM;                // 16384
    uint32_t b01[P];
#pragma unroll
    for (int j = 0; j < P; j++) b01[j] = u01[cid + j * STEP];

    for (int lb = 0; lb < L_DIM; lb += P) {
#pragma unroll
        for (int j = 0; j < P; j++) {
            int l = lb + j;
            uint32_t v01 = b01[j];

            int ln = l + P; if (ln > L_DIM - 1) ln = L_DIM - 1;
            b01[j] = u01[cid + ln * STEP];

            float u0 = bf2f(v01 & 0xFFFFu);
            float u1 = bf2f(v01 >> 16);
            float cp = c;                              // c_prev
            float ef = __expf(-(u1 + fb + cp * fw));
            float f = __builtin_amdgcn_rcpf(1.0f + ef);
            c = u0 + (cp - u0) * f;                    // c_new
            cpack[l * STEP + cid] = (uint32_t)f2bf(cp) | ((uint32_t)f2bf(c) << 16);
        }
    }
    out[L_DIM * STEP + cid] = c;                   // exact fp32 c_final
}

// ---- h: fully parallel, BW-bound, 8 elems/thread, in-place over cpack. ----
// h = xp + (c_new - xp) * sigmoid(u2 + rb + c_prev*rw)   [r uses c_PREV]
__global__ void __launch_bounds__(256)
h_kernel(float* out,                            // in: cpack dwords; out: h fp32
         const uint16_t* __restrict__ u2p,      // M x D bf16 u2
         const float* __restrict__ x,
         const float* __restrict__ wc,
         const float* __restrict__ bias)
{
    size_t i = ((size_t)blockIdx.x * 256 + threadIdx.x) * 8;   // over M*D
    int d0 = (int)(i & (D_DIM - 1));             // 8 consecutive d's, aligned

    u32x4 cv0 = *(const u32x4*)((const uint32_t*)out + i);
    u32x4 cv1 = *(const u32x4*)((const uint32_t*)out + i + 4);
    f32x4 xv0 = *(const f32x4*)(x + i);
    f32x4 xv1 = *(const f32x4*)(x + i + 4);
    ushort8 uv = *(const ushort8*)(u2p + i);
    f32x4 rw0 = *(const f32x4*)(wc + D_DIM + d0);
    f32x4 rw1 = *(const f32x4*)(wc + D_DIM + d0 + 4);
    f32x4 rb0 = *(const f32x4*)(bias + D_DIM + d0);
    f32x4 rb1 = *(const f32x4*)(bias + D_DIM + d0 + 4);

    f32x4 h0, h1;
#pragma unroll
    for (int e = 0; e < 4; e++) {
        uint32_t v = cv0[e];
        float cprev = bf2f(v & 0xFFFFu);
        float cl = bf2f(v >> 16);
        float u2 = bf2f((uint32_t)(unsigned short)uv[e]);
        float xp = xv0[e] * SCALE_X;
        float er = __expf(-(u2 + rb0[e] + cprev * rw0[e]));
        float r = __builtin_amdgcn_rcpf(1.0f + er);
        h0[e] = xp + (cl - xp) * r;
    }
#pragma unroll
    for (int e = 0; e < 4; e++) {
        uint32_t v = cv1[e];
        float cprev = bf2f(v & 0xFFFFu);
        float cl = bf2f(v >> 16);
        float u2 = bf2f((uint32_t)(unsigned short)uv[e + 4]);
        float xp = xv1[e] * SCALE_X;
        float er = __expf(-(u2 + rb1[e] + cprev * rw1[e]));
        float r = __builtin_amdgcn_rcpf(1.0f + er);
        h1[e] = xp + (cl - xp) * r;
    }
    *(f32x4*)(out + i) = h0;
    *(f32x4*)(out + i + 4) = h1;
}

extern "C" void kernel_launch(void* const* d_in, const int* in_sizes, int n_in,
                              void* d_out, int out_size, void* d_ws, size_t ws_size,
                              hipStream_t stream) {
    const float* x    = (const float*)d_in[0];
    const float* c0   = (const float*)d_in[1];
    const float* w    = (const float*)d_in[2];
    const float* wc   = (const float*)d_in[3];
    const float* bias = (const float*)d_in[4];

    // ws layout: wt 6 MB | u2 64 MB | xb 64 MB (fast path only)
    uint16_t* wt  = (uint16_t*)d_ws;
    uint16_t* u2p = (uint16_t*)((char*)d_ws + 6291456);
    const size_t XB_OFF = 6291456 + (size_t)M_DIM * D_DIM * 2;   // 70 MB
    const size_t WS_NEED = XB_OFF + (size_t)M_DIM * K_DIM * 2;   // 134 MB

    uint16_t* u01 = (uint16_t*)d_out;
    float* out = (float*)d_out;

    prep_w_kernel<<<(K_DIM / 32) * (N_DIM / 32), 256, 0, stream>>>(w, wt);

    if (ws_size >= WS_NEED) {
        uint16_t* xb = (uint16_t*)((char*)d_ws + XB_OFF);
        prep_x_kernel<<<(M_DIM * K_DIM / 8) / 256, 256, 0, stream>>>(x, xb);
        gemm_8ph_kernel<<<(M_DIM / 256) * (N_DIM / 256), 512, 0, stream>>>(xb, wt, u01, u2p);
    } else {
        gemm_kernel<<<(M_DIM / 128) * (N_DIM / 128), 256, 0, stream>>>(x, wt, u01, u2p);
    }

    scan_c_kernel<<<(B_DIM * D_DIM) / 64, 64, 0, stream>>>((const uint32_t*)u01,
                                                           (uint32_t*)d_out,
                                                           c0, wc, bias, out);
    h_kernel<<<(M_DIM * D_DIM / 8) / 256, 256, 0, stream>>>(out, u2p, x, wc, bias);
}

// Round 7
// 600.796 us; speedup vs baseline: 1.1641x; 1.0685x over previous
//
#include <hip/hip_runtime.h>
#include <stdint.h>

#define L_DIM 2048
#define B_DIM 16
#define D_DIM 1024
#define M_DIM 32768              // L*B
#define K_DIM 1024               // D
#define N_DIM 3072               // 3D
#define SCALE_X 1.7320508075688772f

typedef __attribute__((ext_vector_type(8))) short short8;
typedef __attribute__((ext_vector_type(8))) unsigned short ushort8;
typedef __attribute__((ext_vector_type(4))) float f32x4;
typedef __attribute__((ext_vector_type(4))) unsigned int u32x4;

__device__ __forceinline__ float bf2f(uint32_t b) {
    union { uint32_t u; float f; } v; v.u = b << 16; return v.f;
}
__device__ __forceinline__ uint16_t f2bf(float f) {
    union { float f; uint32_t u; } v; v.f = f;
    uint32_t u = v.u;
    return (uint16_t)((u + 0x7FFFu + ((u >> 16) & 1u)) >> 16);  // RNE
}

// async global->LDS, 16B per lane. LDS dest is wave-uniform base + lane*16.
__device__ __forceinline__ void gl16(const uint16_t* g, uint16_t* l) {
    __builtin_amdgcn_global_load_lds(
        (const __attribute__((address_space(1))) void*)g,
        (__attribute__((address_space(3))) void*)l,
        16 /*literal*/, 0, 0);
}

// full fence: IR-level memory barrier + MIR scheduling barrier.
__device__ __forceinline__ void fence_all() {
    asm volatile("" ::: "memory");
    __builtin_amdgcn_sched_barrier(0);
}
__device__ __forceinline__ void barrier_hard() {
    fence_all();
    __builtin_amdgcn_s_barrier();
    fence_all();
}

// weight-column permutation: original n = 3d+comp -> storage col s so the
// gemm epilogue writes contiguously: s = comp<2 ? 2d+comp : 2048+d.
__device__ __forceinline__ int perm_n(int n) {
    int dq = n / 3;
    int cm = n - dq * 3;
    return (cm < 2) ? (dq * 2 + cm) : (2048 + dq);
}

// ---- prep: weight (K x N fp32) -> Wt (S x K bf16) with permuted rows ----
__global__ void __launch_bounds__(256)
prep_w_kernel(const float* __restrict__ w, uint16_t* __restrict__ wt) {
    __shared__ uint16_t tile[32][33];            // +1 pad breaks bank conflicts
    int bid = blockIdx.x;
    int kt = (bid & 31) * 32;                    // K/32 = 32
    int nt = (bid >> 5) * 32;                    // N/32 = 96
    int tx = threadIdx.x & 31;
    int ty = threadIdx.x >> 5;                   // 0..7
#pragma unroll
    for (int r = 0; r < 32; r += 8)
        tile[ty + r][tx] = f2bf(w[(size_t)(kt + ty + r) * N_DIM + nt + tx]);
    __syncthreads();
#pragma unroll
    for (int r = 0; r < 32; r += 8) {
        int s = perm_n(nt + ty + r);
        wt[(size_t)s * K_DIM + kt + tx] = tile[tx][ty + r];
    }
}

// ---- prep: x (M x K fp32) -> xb (M x K bf16) ----
__global__ void __launch_bounds__(256)
prep_x_kernel(const float* __restrict__ x, uint16_t* __restrict__ xb) {
    size_t i = (size_t)blockIdx.x * 256 + threadIdx.x;
    const float4 a = *(const float4*)(x + i * 8);
    const float4 b = *(const float4*)(x + i * 8 + 4);
    ushort8 o;
    o[0] = f2bf(a.x); o[1] = f2bf(a.y); o[2] = f2bf(a.z); o[3] = f2bf(a.w);
    o[4] = f2bf(b.x); o[5] = f2bf(b.y); o[6] = f2bf(b.z); o[7] = f2bf(b.w);
    *(ushort8*)(xb + i * 8) = o;
}

// ================= 256x256 8-phase GEMM (T2+T3+T4+T5), hardened =================
// (unchanged from R6 — verified passing)
__global__ void __launch_bounds__(512, 2)
gemm_8ph_kernel(const uint16_t* __restrict__ Ab,  // x bf16, M x K
                const uint16_t* __restrict__ Bt,  // Wt bf16, S x K (permuted)
                uint16_t* __restrict__ u01,       // M x 2048 (aliases d_out)
                uint16_t* __restrict__ u2p)       // M x 1024 (ws)
{
    __shared__ uint16_t lds[65536];               // 128 KiB

    int bid = blockIdx.x;
    int mg = bid / 96;
    int tt = bid - mg * 96;
    int ntile = tt >> 3;
    int mtile = mg * 8 + (tt & 7);
    int m0 = mtile * 256;
    int n0 = ntile * 256;

    int t = threadIdx.x;
    int lane = t & 63;
    int w = t >> 6;
    int wm = (w >> 2) * 128;
    int wn = (w & 3) * 64;

    int row0 = t >> 3;
    int slot = t & 7;
    int swz_c = (slot ^ (row0 & 7)) * 8;
    const uint16_t* pA = Ab + (((size_t)(m0 + row0)) << 10) + swz_c;
    const uint16_t* pB = Bt + (((size_t)(n0 + row0)) << 10) + swz_c;

    int frow = lane & 15;
    int fkb = (lane >> 4) * 16;

    f32x4 acc[8][4] = {};
    short8 aF[4][2];
    short8 bF[4][2];

#define STAGE(hh, Tn) { \
    const uint16_t* gs = (((hh) < 2) ? pA : pB) + ((size_t)((hh) & 1) * 131072) + (size_t)(Tn) * 64; \
    uint16_t* ld = lds + nxtO + (hh) * 8192 + t * 8; \
    gl16(gs, ld); gl16(gs + 65536, ld + 4096); }

#define RD_A(mh) { \
    _Pragma("unroll") for (int mf = 0; mf < 4; mf++) \
    _Pragma("unroll") for (int ks = 0; ks < 2; ks++) { \
        int r = wm + (mh) * 64 + mf * 16 + frow; \
        int cb = (ks * 64 + fkb) ^ ((r & 7) << 4); \
        aF[mf][ks] = *(const short8*)(lds + curA + r * 64 + (cb >> 1)); } }

#define RD_B() { \
    _Pragma("unroll") for (int nf = 0; nf < 4; nf++) \
    _Pragma("unroll") for (int ks = 0; ks < 2; ks++) { \
        int r = wn + nf * 16 + frow; \
        int cb = (ks * 64 + fkb) ^ ((r & 7) << 4); \
        bF[nf][ks] = *(const short8*)(lds + curB + r * 64 + (cb >> 1)); } }

#define QM(mh, nh) { \
    __builtin_amdgcn_s_setprio(1); \
    _Pragma("unroll") for (int mf = 0; mf < 4; mf++) \
    _Pragma("unroll") for (int nj = 0; nj < 2; nj++) \
    _Pragma("unroll") for (int ks = 0; ks < 2; ks++) \
        acc[(mh) * 4 + mf][(nh) * 2 + nj] = __builtin_amdgcn_mfma_f32_16x16x32_bf16( \
            aF[mf][ks], bF[(nh) * 2 + nj][ks], acc[(mh) * 4 + mf][(nh) * 2 + nj], 0, 0, 0); \
    __builtin_amdgcn_s_setprio(0); }

    {
        int nxtO = 0;
        STAGE(0, 0); STAGE(1, 0); STAGE(2, 0); STAGE(3, 0);
    }

    for (int T = 0; T < 15; ++T) {
        int cur = T & 1;
        int curA = cur * 32768;
        int curB = curA + 16384;
        int nxtO = (cur ^ 1) * 32768;

        barrier_hard();                               // all reads of buf[nxt] done
        STAGE(0, T + 1);
        fence_all();
        asm volatile("s_waitcnt vmcnt(2)" ::: "memory");
        barrier_hard();                               // publish tile T
        RD_B();
        RD_A(0);
        QM(0, 0);
        fence_all();
        STAGE(1, T + 1);
        fence_all();
        QM(0, 1);
        RD_A(1);
        fence_all();
        STAGE(2, T + 1);
        fence_all();
        QM(1, 1);
        fence_all();
        STAGE(3, T + 1);
        fence_all();
        QM(1, 0);
    }

    {
        int curA = 32768;
        int curB = curA + 16384;
        barrier_hard();
        asm volatile("s_waitcnt vmcnt(0)" ::: "memory");
        barrier_hard();
        RD_B();
        RD_A(0);
        QM(0, 0);
        QM(0, 1);
        RD_A(1);
        QM(1, 1);
        QM(1, 0);
    }

#undef STAGE
#undef RD_A
#undef RD_B
#undef QM

    int colf = lane & 15;
    int rowq = (lane >> 4) * 4;
#pragma unroll
    for (int i = 0; i < 8; i++) {
#pragma unroll
        for (int j = 0; j < 4; j++) {
            int gcol = n0 + wn + j * 16 + colf;
#pragma unroll
            for (int r = 0; r < 4; r++) {
                int grow = m0 + wm + i * 16 + rowq + r;
                uint16_t v = f2bf(acc[i][j][r]);
                if (gcol < 2048) u01[(size_t)grow * 2048 + gcol] = v;
                else             u2p[(size_t)grow * 1024 + (gcol - 2048)] = v;
            }
        }
    }
}

// ---- fallback GEMM (ws too small for xb): 128^2, A fp32 in-register cvt ----
__global__ void __launch_bounds__(256)
gemm_kernel(const float* __restrict__ A32,
            const uint16_t* __restrict__ Bt,
            uint16_t* __restrict__ u01,
            uint16_t* __restrict__ u2p)
{
    __shared__ uint16_t As[128 * 32];
    __shared__ uint16_t Bs[128 * 32];

    int bid = blockIdx.x;
    int mg = bid / 192;
    int tt = bid - mg * 192;
    int ntile = tt >> 3;
    int mtile = mg * 8 + (tt & 7);
    int m0 = mtile * 128;
    int n0 = ntile * 128;

    int t = threadIdx.x;
    int lane = t & 63;
    int w = t >> 6;
    int wm = (w >> 1) * 64;
    int wn = (w & 1) * 64;

    f32x4 acc[4][4] = {};

    int frow = lane & 15;
    int fk = (lane >> 4) * 8;

    for (int kt = 0; kt < K_DIM; kt += 32) {
#pragma unroll
        for (int c = 0; c < 4; c++) {
            int idx = c * 256 + t;
            int row = idx >> 3;
            int ko = (idx & 7) * 4;
            float4 v = *(const float4*)(A32 + (size_t)(m0 + row) * K_DIM + kt + ko);
            ushort4 o;
            o.x = f2bf(v.x); o.y = f2bf(v.y); o.z = f2bf(v.z); o.w = f2bf(v.w);
            *(ushort4*)(As + row * 32 + ko) = o;
        }
#pragma unroll
        for (int c = 0; c < 2; c++) {
            int idx = c * 256 + t;
            int row = idx >> 2;
            int ko = (idx & 3) * 8;
            short8 v = *(const short8*)(Bt + (size_t)(n0 + row) * K_DIM + kt + ko);
            *(short8*)(Bs + row * 32 + ko) = v;
        }
        __syncthreads();

        short8 af[4], bfr[4];
#pragma unroll
        for (int i = 0; i < 4; i++) {
            af[i]  = *(const short8*)(As + (wm + i * 16 + frow) * 32 + fk);
            bfr[i] = *(const short8*)(Bs + (wn + i * 16 + frow) * 32 + fk);
        }
#pragma unroll
        for (int i = 0; i < 4; i++)
#pragma unroll
            for (int j = 0; j < 4; j++)
                acc[i][j] = __builtin_amdgcn_mfma_f32_16x16x32_bf16(af[i], bfr[j], acc[i][j], 0, 0, 0);
        __syncthreads();
    }

    int colf = lane & 15;
    int rowq = (lane >> 4) * 4;
#pragma unroll
    for (int i = 0; i < 4; i++) {
#pragma unroll
        for (int j = 0; j < 4; j++) {
            int gcol = n0 + wn + j * 16 + colf;
#pragma unroll
            for (int r = 0; r < 4; r++) {
                int grow = m0 + wm + i * 16 + rowq + r;
                uint16_t v = f2bf(acc[i][j][r]);
                if (gcol < 2048) u01[(size_t)grow * 2048 + gcol] = v;
                else             u2p[(size_t)grow * 1024 + (gcol - 2048)] = v;
            }
        }
    }
}

// ---- scan_c: serial c-recurrence. Loads (d_out) and stores (ws cb) are now
// in TRULY DISJOINT buffers with honest __restrict__ -- removes the
// compiler's alias-forced vmem drain per step (the ~234 cy/step floor seen
// across all in-place variants). Stores only bf16(c_new); c_prev is
// reconstructed in h_kernel as cb[l-1] (identical bits to storing it). ----
__global__ void __launch_bounds__(64)
scan_c_kernel(const uint32_t* __restrict__ u01, // M x D of {u0,u1} (d_out)
              uint16_t* __restrict__ cb,        // M x D bf16 c_new (ws, ex-xb)
              const float* __restrict__ c0,
              const float* __restrict__ wc,
              const float* __restrict__ bias,
              float* __restrict__ out)          // c_final fp32 tail (d_out)
{
    int cid = blockIdx.x * 64 + threadIdx.x;       // b*1024 + d
    int d = cid & (D_DIM - 1);
    float fw = wc[d];
    float fb = bias[d];
    float c = c0[cid];

    constexpr int P = 16;
    const int STEP = B_DIM * D_DIM;                // 16384
    uint32_t b01[P];
#pragma unroll
    for (int j = 0; j < P; j++) b01[j] = u01[cid + j * STEP];

    for (int lb = 0; lb < L_DIM; lb += P) {
#pragma unroll
        for (int j = 0; j < P; j++) {
            int l = lb + j;
            uint32_t v01 = b01[j];

            int ln = l + P; if (ln > L_DIM - 1) ln = L_DIM - 1;
            b01[j] = u01[cid + ln * STEP];

            float u0 = bf2f(v01 & 0xFFFFu);
            float u1 = bf2f(v01 >> 16);
            float cp = c;                              // c_prev
            float ef = __expf(-(u1 + fb + cp * fw));
            float f = __builtin_amdgcn_rcpf(1.0f + ef);
            c = u0 + (cp - u0) * f;                    // c_new
            cb[l * STEP + cid] = f2bf(c);
        }
    }
    out[L_DIM * STEP + cid] = c;                   // exact fp32 c_final
}

// ---- h: fully parallel, BW-bound, 8 elems/thread. No aliasing at all:
// reads cb rows l & l-1 (ws), u2p (ws), x (input), c0 (input); writes h
// over the consumed u01 region of d_out.  r uses c_PREV = cb[l-1] (c0 at l=0).
__global__ void __launch_bounds__(256)
h_kernel(float* __restrict__ out,               // d_out: h fp32
         const uint16_t* __restrict__ cb,       // M x D bf16 c_new
         const uint16_t* __restrict__ u2p,      // M x D bf16 u2
         const float* __restrict__ x,
         const float* __restrict__ c0,
         const float* __restrict__ wc,
         const float* __restrict__ bias)
{
    size_t i = ((size_t)blockIdx.x * 256 + threadIdx.x) * 8;   // over M*D
    int d0 = (int)(i & (D_DIM - 1));             // 8 consecutive d's, aligned
    const int STEP = B_DIM * D_DIM;              // 16384

    ushort8 cv = *(const ushort8*)(cb + i);
    f32x4 xv0 = *(const f32x4*)(x + i);
    f32x4 xv1 = *(const f32x4*)(x + i + 4);
    ushort8 uv = *(const ushort8*)(u2p + i);
    f32x4 rw0 = *(const f32x4*)(wc + D_DIM + d0);
    f32x4 rw1 = *(const f32x4*)(wc + D_DIM + d0 + 4);
    f32x4 rb0 = *(const f32x4*)(bias + D_DIM + d0);
    f32x4 rb1 = *(const f32x4*)(bias + D_DIM + d0 + 4);

    float cp[8];
    if (i >= (size_t)STEP) {                     // l >= 1: c_prev = c_new(l-1)
        ushort8 pv = *(const ushort8*)(cb + i - STEP);
#pragma unroll
        for (int e = 0; e < 8; e++) cp[e] = bf2f((uint32_t)(unsigned short)pv[e]);
    } else {                                     // l == 0: c_prev = c0 (fp32)
        f32x4 p0 = *(const f32x4*)(c0 + i);
        f32x4 p1 = *(const f32x4*)(c0 + i + 4);
#pragma unroll
        for (int e = 0; e < 4; e++) { cp[e] = p0[e]; cp[e + 4] = p1[e]; }
    }

    f32x4 h0, h1;
#pragma unroll
    for (int e = 0; e < 4; e++) {
        float cl = bf2f((uint32_t)(unsigned short)cv[e]);
        float u2 = bf2f((uint32_t)(unsigned short)uv[e]);
        float xp = xv0[e] * SCALE_X;
        float er = __expf(-(u2 + rb0[e] + cp[e] * rw0[e]));
        float r = __builtin_amdgcn_rcpf(1.0f + er);
        h0[e] = xp + (cl - xp) * r;
    }
#pragma unroll
    for (int e = 0; e < 4; e++) {
        float cl = bf2f((uint32_t)(unsigned short)cv[e + 4]);
        float u2 = bf2f((uint32_t)(unsigned short)uv[e + 4]);
        float xp = xv1[e] * SCALE_X;
        float er = __expf(-(u2 + rb1[e] + cp[e + 4] * rw1[e]));
        float r = __builtin_amdgcn_rcpf(1.0f + er);
        h1[e] = xp + (cl - xp) * r;
    }
    *(f32x4*)(out + i) = h0;
    *(f32x4*)(out + i + 4) = h1;
}

// ---- fallback scan+h (ws < 134 MB): R6 in-place variants, verified ----
__global__ void __launch_bounds__(64)
scan_c_fb_kernel(const uint32_t* u01, uint32_t* cpack,
                 const float* __restrict__ c0, const float* __restrict__ wc,
                 const float* __restrict__ bias, float* out)
{
    int cid = blockIdx.x * 64 + threadIdx.x;
    int d = cid & (D_DIM - 1);
    float fw = wc[d];
    float fb = bias[d];
    float c = c0[cid];

    constexpr int P = 16;
    const int STEP = B_DIM * D_DIM;
    uint32_t b01[P];
#pragma unroll
    for (int j = 0; j < P; j++) b01[j] = u01[cid + j * STEP];

    for (int lb = 0; lb < L_DIM; lb += P) {
#pragma unroll
        for (int j = 0; j < P; j++) {
            int l = lb + j;
            uint32_t v01 = b01[j];
            int ln = l + P; if (ln > L_DIM - 1) ln = L_DIM - 1;
            b01[j] = u01[cid + ln * STEP];
            float u0 = bf2f(v01 & 0xFFFFu);
            float u1 = bf2f(v01 >> 16);
            float cp = c;
            float ef = __expf(-(u1 + fb + cp * fw));
            float f = __builtin_amdgcn_rcpf(1.0f + ef);
            c = u0 + (cp - u0) * f;
            cpack[l * STEP + cid] = (uint32_t)f2bf(cp) | ((uint32_t)f2bf(c) << 16);
        }
    }
    out[L_DIM * STEP + cid] = c;
}

__global__ void __launch_bounds__(256)
h_fb_kernel(float* out, const uint16_t* __restrict__ u2p,
            const float* __restrict__ x, const float* __restrict__ wc,
            const float* __restrict__ bias)
{
    size_t i = ((size_t)blockIdx.x * 256 + threadIdx.x) * 8;
    int d0 = (int)(i & (D_DIM - 1));

    u32x4 cv0 = *(const u32x4*)((const uint32_t*)out + i);
    u32x4 cv1 = *(const u32x4*)((const uint32_t*)out + i + 4);
    f32x4 xv0 = *(const f32x4*)(x + i);
    f32x4 xv1 = *(const f32x4*)(x + i + 4);
    ushort8 uv = *(const ushort8*)(u2p + i);
    f32x4 rw0 = *(const f32x4*)(wc + D_DIM + d0);
    f32x4 rw1 = *(const f32x4*)(wc + D_DIM + d0 + 4);
    f32x4 rb0 = *(const f32x4*)(bias + D_DIM + d0);
    f32x4 rb1 = *(const f32x4*)(bias + D_DIM + d0 + 4);

    f32x4 h0, h1;
#pragma unroll
    for (int e = 0; e < 4; e++) {
        uint32_t v = cv0[e];
        float cprev = bf2f(v & 0xFFFFu);
        float cl = bf2f(v >> 16);
        float u2 = bf2f((uint32_t)(unsigned short)uv[e]);
        float xp = xv0[e] * SCALE_X;
        float er = __expf(-(u2 + rb0[e] + cprev * rw0[e]));
        float r = __builtin_amdgcn_rcpf(1.0f + er);
        h0[e] = xp + (cl - xp) * r;
    }
#pragma unroll
    for (int e = 0; e < 4; e++) {
        uint32_t v = cv1[e];
        float cprev = bf2f(v & 0xFFFFu);
        float cl = bf2f(v >> 16);
        float u2 = bf2f((uint32_t)(unsigned short)uv[e + 4]);
        float xp = xv1[e] * SCALE_X;
        float er = __expf(-(u2 + rb1[e] + cprev * rw1[e]));
        float r = __builtin_amdgcn_rcpf(1.0f + er);
        h1[e] = xp + (cl - xp) * r;
    }
    *(f32x4*)(out + i) = h0;
    *(f32x4*)(out + i + 4) = h1;
}

extern "C" void kernel_launch(void* const* d_in, const int* in_sizes, int n_in,
                              void* d_out, int out_size, void* d_ws, size_t ws_size,
                              hipStream_t stream) {
    const float* x    = (const float*)d_in[0];
    const float* c0   = (const float*)d_in[1];
    const float* w    = (const float*)d_in[2];
    const float* wc   = (const float*)d_in[3];
    const float* bias = (const float*)d_in[4];

    // ws layout: wt 6 MB | u2 64 MB | xb 64 MB (gemm A), reused as cb (scan c)
    uint16_t* wt  = (uint16_t*)d_ws;
    uint16_t* u2p = (uint16_t*)((char*)d_ws + 6291456);
    const size_t XB_OFF = 6291456 + (size_t)M_DIM * D_DIM * 2;   // 70 MB
    const size_t WS_NEED = XB_OFF + (size_t)M_DIM * K_DIM * 2;   // 134 MB

    uint16_t* u01 = (uint16_t*)d_out;
    float* out = (float*)d_out;

    prep_w_kernel<<<(K_DIM / 32) * (N_DIM / 32), 256, 0, stream>>>(w, wt);

    if (ws_size >= WS_NEED) {
        uint16_t* xb = (uint16_t*)((char*)d_ws + XB_OFF);   // gemm A; dead after
        prep_x_kernel<<<(M_DIM * K_DIM / 8) / 256, 256, 0, stream>>>(x, xb);
        gemm_8ph_kernel<<<(M_DIM / 256) * (N_DIM / 256), 512, 0, stream>>>(xb, wt, u01, u2p);
        uint16_t* cbuf = xb;                                // reuse as c-store
        scan_c_kernel<<<(B_DIM * D_DIM) / 64, 64, 0, stream>>>((const uint32_t*)u01, cbuf,
                                                               c0, wc, bias, out);
        h_kernel<<<(M_DIM * D_DIM / 8) / 256, 256, 0, stream>>>(out, cbuf, u2p, x,
                                                                c0, wc, bias);
    } else {
        gemm_kernel<<<(M_DIM / 128) * (N_DIM / 128), 256, 0, stream>>>(x, wt, u01, u2p);
        scan_c_fb_kernel<<<(B_DIM * D_DIM) / 64, 64, 0, stream>>>((const uint32_t*)u01,
                                                                  (uint32_t*)d_out,
                                                                  c0, wc, bias, out);
        h_fb_kernel<<<(M_DIM * D_DIM / 8) / 256, 256, 0, stream>>>(out, u2p, x, wc, bias);
    }
}